// Round 14
// baseline (131.031 us; speedup 1.0000x reference)
//
#include <hip/hip_runtime.h>
#include <hip/hip_bf16.h>
#include <stdint.h>

typedef __bf16 bf16_t;
typedef __bf16 bf16x4 __attribute__((ext_vector_type(4)));
typedef __bf16 bf16x8 __attribute__((ext_vector_type(8)));
typedef float  f32x4  __attribute__((ext_vector_type(4)));

#define WAITVM(N) asm volatile("s_waitcnt vmcnt(" #N ")" ::: "memory")

// ---- workspace layout (bytes) ----
static constexpr size_t WT_OFF = 0;                    // Wt bf16 [384][1024] = 768 KB
static constexpr size_t Q_OFF  = (size_t)1 << 20;      // q bf16 (pre-scaled 1/32) 4 MB
static constexpr size_t K_OFF  = Q_OFF + ((size_t)4 << 20);
static constexpr size_t VT_OFF = K_OFF + ((size_t)4 << 20);  // vT bf16 [8][128][2048] = 4 MB

__device__ __forceinline__ void g2lds16(const void* g, void* l) {
  __builtin_amdgcn_global_load_lds(
      (__attribute__((address_space(1))) void*)(g),
      (__attribute__((address_space(3))) void*)(l), 16, 0, 0);
}

// ---------------- W transpose: W[1024][128] fp32 -> Wt[384][1024] bf16 ----------------
__global__ __launch_bounds__(256) void wt_kernel(const float* __restrict__ Wq,
                                                 const float* __restrict__ Wk,
                                                 const float* __restrict__ Wv,
                                                 bf16_t* __restrict__ wt) {
  __shared__ float tile[64][129];
  int wi = blockIdx.x >> 4;
  int ct = blockIdx.x & 15;
  const float* W = (wi == 0) ? Wq : ((wi == 1) ? Wk : Wv);
  int c0 = ct * 64;
  int tid = threadIdx.x;
  for (int i = 0; i < 32; ++i) {
    int idx = i * 256 + tid;
    int c = idx >> 7, n = idx & 127;
    tile[c][n] = W[(size_t)(c0 + c) * 128 + n];
  }
  __syncthreads();
  for (int i = 0; i < 32; ++i) {
    int idx = i * 256 + tid;
    int n = idx >> 6, c = idx & 63;
    wt[(size_t)(wi * 128 + n) * 1024 + c0 + c] = (bf16_t)tile[c][n];
  }
}

// ---------------- fused QKV projection v10: barrier-free per-wave register GEMM -----
// Grid 768 = 128 t128-groups x 6 slices(n64), XCD-chunked (96/XCD; co-t slices share
// x via L2). Block 256 thr = 4 independent waves (t32 each). NO LDS, NO barriers.
// Per BK=32 step: 4 wf (bf16x8, L2) + 4 xp (float4, L2/HBM) -> regs, A/B ping-pong
// one step ahead; WAITVM(8) drains set(ks), leaves set(ks+1) in flight; 16 pk-cvt +
// 8 MFMA. ~116 VGPR -> ~4 waves/SIMD; stalls overlap across self-paced waves.
__global__ __launch_bounds__(256) void proj_kernel(const float* __restrict__ x,
                                                   const bf16_t* __restrict__ wt,
                                                   bf16_t* __restrict__ q,
                                                   bf16_t* __restrict__ k,
                                                   bf16_t* __restrict__ vT) {
  int wgid = (blockIdx.x & 7) * 96 + (blockIdx.x >> 3);
  int tgrp = wgid / 6;           // 0..127 -> t128 group
  int sl = wgid % 6;             // qkv = sl>>1 (0=Q,1=K,2=V), nh = sl&1
  int qkv = sl >> 1, nh = sl & 1;
  int n0 = qkv * 128 + nh * 64;

  int tid = threadIdx.x;
  int lane = tid & 63;
  int w = tid >> 6;              // wave's t32 sub-tile
  int lq = lane & 15, grp = lane >> 4;
  int t0 = tgrp * 128 + w * 32;

  const float* xr0 = x + (size_t)(t0 + lq) * 1024 + grp * 8;        // sub=0 x row
  const float* xr1 = x + (size_t)(t0 + 16 + lq) * 1024 + grp * 8;   // sub=1 x row
  const bf16_t* wb = wt + (size_t)(n0 + lq) * 1024 + grp * 8;       // +a*16 rows

  f32x4 acc[4][2];               // [a][sub]
#pragma unroll
  for (int a = 0; a < 4; ++a)
#pragma unroll
    for (int s = 0; s < 2; ++s) acc[a][s] = (f32x4){0.f, 0.f, 0.f, 0.f};

  bf16x8 wfA[4], wfB[4];
  float4 xpA[4], xpB[4];

#define LOADSET(WF, XP, K0)                                                   \
  do {                                                                        \
    WF[0] = *(const bf16x8*)(wb + 0 * 16384 + (K0));                          \
    WF[1] = *(const bf16x8*)(wb + 1 * 16384 + (K0));                          \
    WF[2] = *(const bf16x8*)(wb + 2 * 16384 + (K0));                          \
    WF[3] = *(const bf16x8*)(wb + 3 * 16384 + (K0));                          \
    XP[0] = *(const float4*)(xr0 + (K0));                                     \
    XP[1] = *(const float4*)(xr0 + (K0) + 4);                                 \
    XP[2] = *(const float4*)(xr1 + (K0));                                     \
    XP[3] = *(const float4*)(xr1 + (K0) + 4);                                 \
  } while (0)

#define COMPUTE(WF, XP)                                                       \
  do {                                                                        \
    bf16x8 xf0, xf1;                                                          \
    xf0[0] = (bf16_t)XP[0].x; xf0[1] = (bf16_t)XP[0].y;                       \
    xf0[2] = (bf16_t)XP[0].z; xf0[3] = (bf16_t)XP[0].w;                       \
    xf0[4] = (bf16_t)XP[1].x; xf0[5] = (bf16_t)XP[1].y;                       \
    xf0[6] = (bf16_t)XP[1].z; xf0[7] = (bf16_t)XP[1].w;                       \
    xf1[0] = (bf16_t)XP[2].x; xf1[1] = (bf16_t)XP[2].y;                       \
    xf1[2] = (bf16_t)XP[2].z; xf1[3] = (bf16_t)XP[2].w;                       \
    xf1[4] = (bf16_t)XP[3].x; xf1[5] = (bf16_t)XP[3].y;                       \
    xf1[6] = (bf16_t)XP[3].z; xf1[7] = (bf16_t)XP[3].w;                       \
    _Pragma("unroll") for (int a = 0; a < 4; ++a) {                           \
      acc[a][0] = __builtin_amdgcn_mfma_f32_16x16x32_bf16(WF[a], xf0, acc[a][0], 0, 0, 0); \
      acc[a][1] = __builtin_amdgcn_mfma_f32_16x16x32_bf16(WF[a], xf1, acc[a][1], 0, 0, 0); \
    }                                                                         \
  } while (0)

  LOADSET(wfA, xpA, 0);

#pragma unroll 1
  for (int it = 0; it < 16; ++it) {
    int kA = it * 64;                  // step A k0 = 64*it, step B k0 = 64*it+32
    LOADSET(wfB, xpB, kA + 32);        // queue: [A:8, B:8]
    WAITVM(8);                         // A landed; B in flight
    __builtin_amdgcn_sched_barrier(0);
    COMPUTE(wfA, xpA);
    if (it < 15) {
      LOADSET(wfA, xpA, kA + 64);      // queue: [B:8, A':8]
      WAITVM(8);                       // B landed; A' in flight
    } else {
      WAITVM(0);
    }
    __builtin_amdgcn_sched_barrier(0);
    COMPUTE(wfB, xpB);
  }
#undef LOADSET
#undef COMPUTE

  if (qkv < 2) {   // Q (pre-scaled 1/32, exact in bf16) or K, row-major [t][128]
    bf16_t* dst = (qkv == 0) ? q : k;
    float qs = (qkv == 0) ? 0.03125f : 1.0f;
#pragma unroll
    for (int a = 0; a < 4; ++a)
#pragma unroll
      for (int sub = 0; sub < 2; ++sub) {
        bf16x4 o;
        o[0] = (bf16_t)(acc[a][sub][0] * qs); o[1] = (bf16_t)(acc[a][sub][1] * qs);
        o[2] = (bf16_t)(acc[a][sub][2] * qs); o[3] = (bf16_t)(acc[a][sub][3] * qs);
        *(bf16x4*)(dst + (size_t)(t0 + sub * 16 + lq) * 128
                   + nh * 64 + a * 16 + grp * 4) = o;
      }
  } else {         // V transposed: vT[b][d][t]
    int b = t0 >> 11;
#pragma unroll
    for (int a = 0; a < 4; ++a)
#pragma unroll
      for (int sub = 0; sub < 2; ++sub) {
        int tt = (t0 + sub * 16 + lq) & 2047;
#pragma unroll
        for (int r = 0; r < 4; ++r) {
          int d = nh * 64 + a * 16 + grp * 4 + r;
          vT[(size_t)b * 128 * 2048 + (size_t)d * 2048 + tt] = (bf16_t)acc[a][sub][r];
        }
      }
  }
}

// ---------------- flash attention v11 (unchanged: measured ~30us) -------------------
__global__ __launch_bounds__(512) void attn_kernel(const bf16_t* __restrict__ q,
                                                   const bf16_t* __restrict__ k,
                                                   const bf16_t* __restrict__ vT,
                                                   float* __restrict__ out) {
  __shared__ __align__(16) char lds[81920];

  int tid = threadIdx.x;
  int lane = tid & 63;
  int w = tid >> 6;                  // kv-split index 0..7
  int lq = lane & 15, grp = lane >> 4;
  int b = blockIdx.x & 7;            // XCD-pinned batch
  int qt = 63 - (blockIdx.x >> 3);   // heavy first; 32 q-rows
  int tq0 = qt * 32 + lq;            // qh=0 row; qh=1 row = tq0+16

  bf16x8 qf[4][2];
#pragma unroll
  for (int qh = 0; qh < 2; ++qh) {
    const bf16_t* qrow = q + ((size_t)b * 2048 + tq0 + qh * 16) * 128 + grp * 8;
#pragma unroll
    for (int ks = 0; ks < 4; ++ks) qf[ks][qh] = *(const bf16x8*)(qrow + ks * 32);
  }

  float mrun[2] = {-__builtin_inff(), -__builtin_inff()};
  float lsum[2] = {0.f, 0.f};
  f32x4 accO[8][2];
#pragma unroll
  for (int i = 0; i < 8; ++i)
#pragma unroll
    for (int qh = 0; qh < 2; ++qh) accO[i][qh] = (f32x4){0.f, 0.f, 0.f, 0.f};

  const char* kbase = (const char*)(k + (size_t)b * 2048 * 128);
  const bf16_t* vb = vT + (size_t)b * 128 * 2048;

  auto stageK = [&](int kv0) {
#pragma unroll
    for (int i = 0; i < 8; ++i) {
      int off = i * 1024 + lane * 16;
      int row = off >> 8;
      int c = (off >> 4) & 15;
      const char* src = kbase + (size_t)(kv0 + row) * 256 + ((c ^ (row & 7)) << 4);
      g2lds16(src, &lds[w * 8192 + off]);
    }
  };

  bf16x8 vf[8];
  auto loadV = [&](int kv0) {
#pragma unroll
    for (int mf = 0; mf < 8; ++mf)
      vf[mf] = *(const bf16x8*)(vb + (size_t)(mf * 16 + lq) * 2048 + kv0 + grp * 8);
  };

  int nt = qt + 1;
  int cnt = (nt - w + 7) >> 3;

  if (cnt > 0) { stageK(w * 32); loadV(w * 32); }

#pragma unroll 1
  for (int i = 0; i < cnt; ++i) {
    int kv0 = (w + 8 * i) * 32;
    bool pre = (i + 1 < cnt);

    WAITVM(8);
    __builtin_amdgcn_sched_barrier(0);

    f32x4 s[2][2];
#pragma unroll
    for (int mf = 0; mf < 2; ++mf)
#pragma unroll
      for (int qh = 0; qh < 2; ++qh) s[mf][qh] = (f32x4){0.f, 0.f, 0.f, 0.f};
#pragma unroll
    for (int ks = 0; ks < 4; ++ks)
#pragma unroll
      for (int mf = 0; mf < 2; ++mf) {
        int row = mf * 16 + lq;
        bf16x8 kf = *(const bf16x8*)(&lds[w * 8192 + row * 256
                                          + (((ks * 4 + grp) ^ (row & 7)) << 4)]);
#pragma unroll
        for (int qh = 0; qh < 2; ++qh)
          s[mf][qh] = __builtin_amdgcn_mfma_f32_16x16x32_bf16(kf, qf[ks][qh], s[mf][qh], 0, 0, 0);
      }

    asm volatile("s_waitcnt lgkmcnt(0)" ::: "memory");
    __builtin_amdgcn_sched_barrier(0);
    if (pre) stageK(kv0 + 256);

#pragma unroll
    for (int qh = 0; qh < 2; ++qh) {
      int tq = tq0 + qh * 16;
      bool hasmask = (kv0 + 31 > qt * 32 + qh * 16);
      if (hasmask) {
#pragma unroll
        for (int f = 0; f < 2; ++f)
#pragma unroll
          for (int r = 0; r < 4; ++r) {
            int kv = kv0 + f * 16 + grp * 4 + r;
            s[f][qh][r] = (kv <= tq) ? s[f][qh][r] : -__builtin_inff();
          }
      }
      float pmax = -__builtin_inff();
#pragma unroll
      for (int f = 0; f < 2; ++f)
#pragma unroll
        for (int r = 0; r < 4; ++r) pmax = fmaxf(pmax, s[f][qh][r]);
      pmax = fmaxf(pmax, __shfl_xor(pmax, 16, 64));
      pmax = fmaxf(pmax, __shfl_xor(pmax, 32, 64));

      float msub;
      if (__all(pmax <= mrun[qh])) {
        msub = mrun[qh];
      } else {
        float mnew = fmaxf(mrun[qh], pmax);
        msub = fmaxf(mnew, -3e38f);
        float corr = __expf(mrun[qh] - msub);
        lsum[qh] *= corr;
        mrun[qh] = mnew;
#pragma unroll
        for (int i2 = 0; i2 < 8; ++i2) accO[i2][qh] *= corr;
      }

      float psum = 0.f;
#pragma unroll
      for (int f = 0; f < 2; ++f) {
        bf16x4 pw;
#pragma unroll
        for (int r = 0; r < 4; ++r) {
          float pe = __expf(s[f][qh][r] - msub);
          psum += pe;
          pw[r] = (bf16_t)pe;
        }
        *(bf16x4*)(&lds[65536 + w * 2048 + qh * 1024 + ((f * 2 + (grp >> 1)) << 8)
                        + lq * 16 + ((grp & 1) << 3)]) = pw;
      }
      psum += __shfl_xor(psum, 16, 64);
      psum += __shfl_xor(psum, 32, 64);
      lsum[qh] += psum;
    }

    if (pre) { WAITVM(8); }
    else     { WAITVM(0); }
    __builtin_amdgcn_sched_barrier(0);

    bf16x8 pf0 = *(const bf16x8*)(&lds[65536 + w * 2048 + (grp << 8) + lq * 16]);
    bf16x8 pf1 = *(const bf16x8*)(&lds[65536 + w * 2048 + 1024 + (grp << 8) + lq * 16]);
#pragma unroll
    for (int mf = 0; mf < 8; ++mf) {
      accO[mf][0] = __builtin_amdgcn_mfma_f32_16x16x32_bf16(vf[mf], pf0, accO[mf][0], 0, 0, 0);
      accO[mf][1] = __builtin_amdgcn_mfma_f32_16x16x32_bf16(vf[mf], pf1, accO[mf][1], 0, 0, 0);
    }

    if (pre) loadV(kv0 + 256);
  }

  // ---- 8-way kv-split merge: 3-round LDS tree ----
#pragma unroll 1
  for (int round = 0; round < 3; ++round) {
    int stride = 4 >> round;
    __syncthreads();
    if (w >= stride && w < 2 * stride) {
      int slot = w - stride;
#pragma unroll
      for (int qh = 0; qh < 2; ++qh) {
#pragma unroll
        for (int mf = 0; mf < 8; ++mf)
          *(f32x4*)(&lds[slot * 16384 + qh * 8192 + mf * 1024 + lane * 16]) = accO[mf][qh];
        *(float*)(&lds[65536 + w * 2048 + qh * 512 + lane * 8])     = mrun[qh];
        *(float*)(&lds[65536 + w * 2048 + qh * 512 + lane * 8 + 4]) = lsum[qh];
      }
    }
    __syncthreads();
    if (w < stride) {
      int pw = w + stride;
#pragma unroll
      for (int qh = 0; qh < 2; ++qh) {
        float mB = *(const float*)(&lds[65536 + pw * 2048 + qh * 512 + lane * 8]);
        float lB = *(const float*)(&lds[65536 + pw * 2048 + qh * 512 + lane * 8 + 4]);
        float mN = fmaxf(mrun[qh], mB);
        float ms = fmaxf(mN, -3e38f);
        float cA = __expf(mrun[qh] - ms);
        float cB = __expf(mB - ms);
        lsum[qh] = lsum[qh] * cA + lB * cB;
        mrun[qh] = mN;
#pragma unroll
        for (int mf = 0; mf < 8; ++mf) {
          f32x4 OB = *(const f32x4*)(&lds[w * 16384 + qh * 8192 + mf * 1024 + lane * 16]);
#pragma unroll
          for (int e = 0; e < 4; ++e) accO[mf][qh][e] = accO[mf][qh][e] * cA + OB[e] * cB;
        }
      }
    }
  }

  if (w == 0) {
#pragma unroll
    for (int qh = 0; qh < 2; ++qh) {
      float inv = 1.0f / lsum[qh];
      float* orow = out + ((size_t)b * 2048 + tq0 + qh * 16) * 128;
#pragma unroll
      for (int mf = 0; mf < 8; ++mf) {
        f32x4 o;
#pragma unroll
        for (int e = 0; e < 4; ++e) o[e] = accO[mf][qh][e] * inv;
        *(f32x4*)(orow + mf * 16 + grp * 4) = o;
      }
    }
  }
}

extern "C" void kernel_launch(void* const* d_in, const int* in_sizes, int n_in,
                              void* d_out, int out_size, void* d_ws, size_t ws_size,
                              hipStream_t stream) {
  const float* x  = (const float*)d_in[0];
  const float* Wq = (const float*)d_in[1];
  const float* Wk = (const float*)d_in[2];
  const float* Wv = (const float*)d_in[3];
  float* out = (float*)d_out;
  char* ws = (char*)d_ws;

  bf16_t* wt = (bf16_t*)(ws + WT_OFF);
  bf16_t* qb = (bf16_t*)(ws + Q_OFF);
  bf16_t* kb = (bf16_t*)(ws + K_OFF);
  bf16_t* vT = (bf16_t*)(ws + VT_OFF);

  hipLaunchKernelGGL(wt_kernel, dim3(48), dim3(256), 0, stream, Wq, Wk, Wv, wt);
  hipLaunchKernelGGL(proj_kernel, dim3(768), dim3(256), 0, stream, x, wt, qb, kb, vT);
  hipLaunchKernelGGL(attn_kernel, dim3(512), dim3(512), 0, stream, qb, kb, vT, out);
}

// Round 15
// 79.645 us; speedup vs baseline: 1.6452x; 1.6452x over previous
//
#include <hip/hip_runtime.h>
#include <hip/hip_bf16.h>
#include <stdint.h>

typedef __bf16 bf16_t;
typedef __bf16 bf16x4 __attribute__((ext_vector_type(4)));
typedef __bf16 bf16x8 __attribute__((ext_vector_type(8)));
typedef float  f32x4  __attribute__((ext_vector_type(4)));

#define WAITVM(N) asm volatile("s_waitcnt vmcnt(" #N ")" ::: "memory")

// ---- workspace layout (bytes) ----
static constexpr size_t WT_OFF = 0;                    // Wt bf16 [384][1024] = 768 KB
static constexpr size_t Q_OFF  = (size_t)1 << 20;      // q bf16 (pre-scaled 1/32) 4 MB
static constexpr size_t K_OFF  = Q_OFF + ((size_t)4 << 20);
static constexpr size_t VT_OFF = K_OFF + ((size_t)4 << 20);  // vT bf16 [8][128][2048] = 4 MB

__device__ __forceinline__ void g2lds16(const void* g, void* l) {
  __builtin_amdgcn_global_load_lds(
      (__attribute__((address_space(1))) void*)(g),
      (__attribute__((address_space(3))) void*)(l), 16, 0, 0);
}

// ---------------- W transpose: W[1024][128] fp32 -> Wt[384][1024] bf16 ----------------
__global__ __launch_bounds__(256) void wt_kernel(const float* __restrict__ Wq,
                                                 const float* __restrict__ Wk,
                                                 const float* __restrict__ Wv,
                                                 bf16_t* __restrict__ wt) {
  __shared__ float tile[64][129];
  int wi = blockIdx.x >> 4;
  int ct = blockIdx.x & 15;
  const float* W = (wi == 0) ? Wq : ((wi == 1) ? Wk : Wv);
  int c0 = ct * 64;
  int tid = threadIdx.x;
  for (int i = 0; i < 32; ++i) {
    int idx = i * 256 + tid;
    int c = idx >> 7, n = idx & 127;
    tile[c][n] = W[(size_t)(c0 + c) * 128 + n];
  }
  __syncthreads();
  for (int i = 0; i < 32; ++i) {
    int idx = i * 256 + tid;
    int n = idx >> 6, c = idx & 63;
    wt[(size_t)(wi * 128 + n) * 1024 + c0 + c] = (bf16_t)tile[c][n];
  }
}

// ---------------- fused QKV projection v11: v6 + wt through LDS ---------------------
// Grid 768 = 3 slices(n128) x 256 t-tiles(64), XCD-chunked. Block 256 thr = 4 waves
// (n32 quarters). BOTH operands g2lds-staged one full step ahead (zero VMEM latency
// on critical path): Xlds 2x16KB fp32 (v6 swizzle, 0 conflicts) + Wlds 2x16KB bf16
// (chunk^(row&7)). Per step/thread: 8 g2lds; WAITVM(8); barrier; per wave: 4 wf-ds_read
// + 8 xf-ds_read + cvt + 16 MFMA; barrier. 64KB LDS -> 2 blocks/CU + backfill.
__global__ __launch_bounds__(256) void proj_kernel(const float* __restrict__ x,
                                                   const bf16_t* __restrict__ wt,
                                                   bf16_t* __restrict__ q,
                                                   bf16_t* __restrict__ k,
                                                   bf16_t* __restrict__ vT) {
  __shared__ __align__(16) char Xlds[2][16384];  // x tile [64 t][64 k] f32, swz c^(row&15)
  __shared__ __align__(16) char Wlds[2][16384];  // wt tile [128 n][64 k] bf16, swz c^(row&7)

  int wgid = (blockIdx.x & 7) * 96 + (blockIdx.x >> 3);
  int t_tile = wgid / 3;
  int slice = wgid % 3;          // 0=Q, 1=K, 2=V
  int n0 = slice * 128;
  int t0 = t_tile * 64;

  int tid = threadIdx.x;
  int lane = tid & 63;
  int nq = tid >> 6;             // wave = n32 quarter
  int lq = lane & 15, grp = lane >> 4;

  const char* xb = (const char*)x;            // row stride 4096 B
  const char* wb = (const char*)wt;           // row stride 2048 B

  f32x4 acc[2][4];
#pragma unroll
  for (int a = 0; a < 2; ++a)
#pragma unroll
    for (int s = 0; s < 4; ++s) acc[a][s] = (f32x4){0.f, 0.f, 0.f, 0.f};

  auto stageX = [&](int bi, int k0) {   // 4 x g2lds16 per thread (16KB tile)
#pragma unroll
    for (int i = 0; i < 4; ++i) {
      int off = i * 4096 + tid * 16;
      int row = off >> 8;               // 0..63 (256B rows)
      int c = (off >> 4) & 15;
      const char* src = xb + (size_t)(t0 + row) * 4096 + (size_t)k0 * 4
                        + ((c ^ (row & 15)) << 4);
      g2lds16(src, &Xlds[bi][off]);
    }
  };
  auto stageW = [&](int bi, int k0) {   // 4 x g2lds16 per thread (16KB tile)
#pragma unroll
    for (int i = 0; i < 4; ++i) {
      int off = i * 4096 + tid * 16;
      int row = off >> 7;               // 0..127 (128B rows)
      int c = (off >> 4) & 7;
      const char* src = wb + (size_t)(n0 + row) * 2048 + (size_t)k0 * 2
                        + ((c ^ (row & 7)) << 4);
      g2lds16(src, &Wlds[bi][off]);
    }
  };

  stageX(0, 0);
  stageW(0, 0);

#pragma unroll 1
  for (int ks = 0; ks < 16; ++ks) {
    int cur = ks & 1;

    if (ks < 15) {
      stageX(cur ^ 1, (ks + 1) * 64);
      stageW(cur ^ 1, (ks + 1) * 64);
      WAITVM(8);                 // stage(ks) landed; stage(ks+1) stays in flight
    } else {
      WAITVM(0);
    }
    __builtin_amdgcn_s_barrier();
    __builtin_amdgcn_sched_barrier(0);

    // wf frags from Wlds (swizzled, <=2-way)
    bf16x8 wf[2][2];
#pragma unroll
    for (int a = 0; a < 2; ++a) {
      int row = nq * 32 + a * 16 + lq;
#pragma unroll
      for (int kh = 0; kh < 2; ++kh) {
        int sw = (row << 7) | ((((kh << 2) | grp) ^ (row & 7)) << 4);
        wf[a][kh] = *(const bf16x8*)(&Wlds[cur][sw]);
      }
    }

    // xf frags from Xlds (fp32 -> bf16 cvt, v6 pattern)
    bf16x8 xf[4][2];
#pragma unroll
    for (int sub = 0; sub < 4; ++sub) {
      int row = sub * 16 + lq;
#pragma unroll
      for (int kh = 0; kh < 2; ++kh) {
        int c0 = kh * 8 + grp * 2;
        float4 f0 = *(const float4*)(&Xlds[cur][(row << 8) | (((c0)     ^ (row & 15)) << 4)]);
        float4 f1 = *(const float4*)(&Xlds[cur][(row << 8) | (((c0 + 1) ^ (row & 15)) << 4)]);
        bf16x8 v;
        v[0] = (bf16_t)f0.x; v[1] = (bf16_t)f0.y; v[2] = (bf16_t)f0.z; v[3] = (bf16_t)f0.w;
        v[4] = (bf16_t)f1.x; v[5] = (bf16_t)f1.y; v[6] = (bf16_t)f1.z; v[7] = (bf16_t)f1.w;
        xf[sub][kh] = v;
      }
    }

#pragma unroll
    for (int kh = 0; kh < 2; ++kh)
#pragma unroll
      for (int a = 0; a < 2; ++a)
#pragma unroll
        for (int sub = 0; sub < 4; ++sub)
          acc[a][sub] = __builtin_amdgcn_mfma_f32_16x16x32_bf16(wf[a][kh], xf[sub][kh],
                                                                acc[a][sub], 0, 0, 0);
    __builtin_amdgcn_s_barrier();   // all waves done with buf cur
  }

  if (slice < 2) {   // Q (pre-scaled 1/32, exact in bf16) or K, row-major [t][128]
    bf16_t* dst = (slice == 0) ? q : k;
    float qs = (slice == 0) ? 0.03125f : 1.0f;
#pragma unroll
    for (int a = 0; a < 2; ++a)
#pragma unroll
      for (int sub = 0; sub < 4; ++sub) {
        bf16x4 o;
        o[0] = (bf16_t)(acc[a][sub][0] * qs); o[1] = (bf16_t)(acc[a][sub][1] * qs);
        o[2] = (bf16_t)(acc[a][sub][2] * qs); o[3] = (bf16_t)(acc[a][sub][3] * qs);
        *(bf16x4*)(dst + (size_t)(t0 + sub * 16 + lq) * 128
                   + nq * 32 + a * 16 + grp * 4) = o;
      }
  } else {           // V transposed: vT[b][d][t]
    int b = t0 >> 11;
#pragma unroll
    for (int a = 0; a < 2; ++a)
#pragma unroll
      for (int sub = 0; sub < 4; ++sub) {
        int tt = (t0 + sub * 16 + lq) & 2047;
#pragma unroll
        for (int r = 0; r < 4; ++r) {
          int d = nq * 32 + a * 16 + grp * 4 + r;
          vT[(size_t)b * 128 * 2048 + (size_t)d * 2048 + tt] = (bf16_t)acc[a][sub][r];
        }
      }
  }
}

// ---------------- flash attention v11 (unchanged: measured ~30us) -------------------
__global__ __launch_bounds__(512) void attn_kernel(const bf16_t* __restrict__ q,
                                                   const bf16_t* __restrict__ k,
                                                   const bf16_t* __restrict__ vT,
                                                   float* __restrict__ out) {
  __shared__ __align__(16) char lds[81920];

  int tid = threadIdx.x;
  int lane = tid & 63;
  int w = tid >> 6;                  // kv-split index 0..7
  int lq = lane & 15, grp = lane >> 4;
  int b = blockIdx.x & 7;            // XCD-pinned batch
  int qt = 63 - (blockIdx.x >> 3);   // heavy first; 32 q-rows
  int tq0 = qt * 32 + lq;            // qh=0 row; qh=1 row = tq0+16

  bf16x8 qf[4][2];
#pragma unroll
  for (int qh = 0; qh < 2; ++qh) {
    const bf16_t* qrow = q + ((size_t)b * 2048 + tq0 + qh * 16) * 128 + grp * 8;
#pragma unroll
    for (int ks = 0; ks < 4; ++ks) qf[ks][qh] = *(const bf16x8*)(qrow + ks * 32);
  }

  float mrun[2] = {-__builtin_inff(), -__builtin_inff()};
  float lsum[2] = {0.f, 0.f};
  f32x4 accO[8][2];
#pragma unroll
  for (int i = 0; i < 8; ++i)
#pragma unroll
    for (int qh = 0; qh < 2; ++qh) accO[i][qh] = (f32x4){0.f, 0.f, 0.f, 0.f};

  const char* kbase = (const char*)(k + (size_t)b * 2048 * 128);
  const bf16_t* vb = vT + (size_t)b * 128 * 2048;

  auto stageK = [&](int kv0) {
#pragma unroll
    for (int i = 0; i < 8; ++i) {
      int off = i * 1024 + lane * 16;
      int row = off >> 8;
      int c = (off >> 4) & 15;
      const char* src = kbase + (size_t)(kv0 + row) * 256 + ((c ^ (row & 7)) << 4);
      g2lds16(src, &lds[w * 8192 + off]);
    }
  };

  bf16x8 vf[8];
  auto loadV = [&](int kv0) {
#pragma unroll
    for (int mf = 0; mf < 8; ++mf)
      vf[mf] = *(const bf16x8*)(vb + (size_t)(mf * 16 + lq) * 2048 + kv0 + grp * 8);
  };

  int nt = qt + 1;
  int cnt = (nt - w + 7) >> 3;

  if (cnt > 0) { stageK(w * 32); loadV(w * 32); }

#pragma unroll 1
  for (int i = 0; i < cnt; ++i) {
    int kv0 = (w + 8 * i) * 32;
    bool pre = (i + 1 < cnt);

    WAITVM(8);
    __builtin_amdgcn_sched_barrier(0);

    f32x4 s[2][2];
#pragma unroll
    for (int mf = 0; mf < 2; ++mf)
#pragma unroll
      for (int qh = 0; qh < 2; ++qh) s[mf][qh] = (f32x4){0.f, 0.f, 0.f, 0.f};
#pragma unroll
    for (int ks = 0; ks < 4; ++ks)
#pragma unroll
      for (int mf = 0; mf < 2; ++mf) {
        int row = mf * 16 + lq;
        bf16x8 kf = *(const bf16x8*)(&lds[w * 8192 + row * 256
                                          + (((ks * 4 + grp) ^ (row & 7)) << 4)]);
#pragma unroll
        for (int qh = 0; qh < 2; ++qh)
          s[mf][qh] = __builtin_amdgcn_mfma_f32_16x16x32_bf16(kf, qf[ks][qh], s[mf][qh], 0, 0, 0);
      }

    asm volatile("s_waitcnt lgkmcnt(0)" ::: "memory");
    __builtin_amdgcn_sched_barrier(0);
    if (pre) stageK(kv0 + 256);

#pragma unroll
    for (int qh = 0; qh < 2; ++qh) {
      int tq = tq0 + qh * 16;
      bool hasmask = (kv0 + 31 > qt * 32 + qh * 16);
      if (hasmask) {
#pragma unroll
        for (int f = 0; f < 2; ++f)
#pragma unroll
          for (int r = 0; r < 4; ++r) {
            int kv = kv0 + f * 16 + grp * 4 + r;
            s[f][qh][r] = (kv <= tq) ? s[f][qh][r] : -__builtin_inff();
          }
      }
      float pmax = -__builtin_inff();
#pragma unroll
      for (int f = 0; f < 2; ++f)
#pragma unroll
        for (int r = 0; r < 4; ++r) pmax = fmaxf(pmax, s[f][qh][r]);
      pmax = fmaxf(pmax, __shfl_xor(pmax, 16, 64));
      pmax = fmaxf(pmax, __shfl_xor(pmax, 32, 64));

      float msub;
      if (__all(pmax <= mrun[qh])) {
        msub = mrun[qh];
      } else {
        float mnew = fmaxf(mrun[qh], pmax);
        msub = fmaxf(mnew, -3e38f);
        float corr = __expf(mrun[qh] - msub);
        lsum[qh] *= corr;
        mrun[qh] = mnew;
#pragma unroll
        for (int i2 = 0; i2 < 8; ++i2) accO[i2][qh] *= corr;
      }

      float psum = 0.f;
#pragma unroll
      for (int f = 0; f < 2; ++f) {
        bf16x4 pw;
#pragma unroll
        for (int r = 0; r < 4; ++r) {
          float pe = __expf(s[f][qh][r] - msub);
          psum += pe;
          pw[r] = (bf16_t)pe;
        }
        *(bf16x4*)(&lds[65536 + w * 2048 + qh * 1024 + ((f * 2 + (grp >> 1)) << 8)
                        + lq * 16 + ((grp & 1) << 3)]) = pw;
      }
      psum += __shfl_xor(psum, 16, 64);
      psum += __shfl_xor(psum, 32, 64);
      lsum[qh] += psum;
    }

    if (pre) { WAITVM(8); }
    else     { WAITVM(0); }
    __builtin_amdgcn_sched_barrier(0);

    bf16x8 pf0 = *(const bf16x8*)(&lds[65536 + w * 2048 + (grp << 8) + lq * 16]);
    bf16x8 pf1 = *(const bf16x8*)(&lds[65536 + w * 2048 + 1024 + (grp << 8) + lq * 16]);
#pragma unroll
    for (int mf = 0; mf < 8; ++mf) {
      accO[mf][0] = __builtin_amdgcn_mfma_f32_16x16x32_bf16(vf[mf], pf0, accO[mf][0], 0, 0, 0);
      accO[mf][1] = __builtin_amdgcn_mfma_f32_16x16x32_bf16(vf[mf], pf1, accO[mf][1], 0, 0, 0);
    }

    if (pre) loadV(kv0 + 256);
  }

  // ---- 8-way kv-split merge: 3-round LDS tree ----
#pragma unroll 1
  for (int round = 0; round < 3; ++round) {
    int stride = 4 >> round;
    __syncthreads();
    if (w >= stride && w < 2 * stride) {
      int slot = w - stride;
#pragma unroll
      for (int qh = 0; qh < 2; ++qh) {
#pragma unroll
        for (int mf = 0; mf < 8; ++mf)
          *(f32x4*)(&lds[slot * 16384 + qh * 8192 + mf * 1024 + lane * 16]) = accO[mf][qh];
        *(float*)(&lds[65536 + w * 2048 + qh * 512 + lane * 8])     = mrun[qh];
        *(float*)(&lds[65536 + w * 2048 + qh * 512 + lane * 8 + 4]) = lsum[qh];
      }
    }
    __syncthreads();
    if (w < stride) {
      int pw = w + stride;
#pragma unroll
      for (int qh = 0; qh < 2; ++qh) {
        float mB = *(const float*)(&lds[65536 + pw * 2048 + qh * 512 + lane * 8]);
        float lB = *(const float*)(&lds[65536 + pw * 2048 + qh * 512 + lane * 8 + 4]);
        float mN = fmaxf(mrun[qh], mB);
        float ms = fmaxf(mN, -3e38f);
        float cA = __expf(mrun[qh] - ms);
        float cB = __expf(mB - ms);
        lsum[qh] = lsum[qh] * cA + lB * cB;
        mrun[qh] = mN;
#pragma unroll
        for (int mf = 0; mf < 8; ++mf) {
          f32x4 OB = *(const f32x4*)(&lds[w * 16384 + qh * 8192 + mf * 1024 + lane * 16]);
#pragma unroll
          for (int e = 0; e < 4; ++e) accO[mf][qh][e] = accO[mf][qh][e] * cA + OB[e] * cB;
        }
      }
    }
  }

  if (w == 0) {
#pragma unroll
    for (int qh = 0; qh < 2; ++qh) {
      float inv = 1.0f / lsum[qh];
      float* orow = out + ((size_t)b * 2048 + tq0 + qh * 16) * 128;
#pragma unroll
      for (int mf = 0; mf < 8; ++mf) {
        f32x4 o;
#pragma unroll
        for (int e = 0; e < 4; ++e) o[e] = accO[mf][qh][e] * inv;
        *(f32x4*)(orow + mf * 16 + grp * 4) = o;
      }
    }
  }
}

extern "C" void kernel_launch(void* const* d_in, const int* in_sizes, int n_in,
                              void* d_out, int out_size, void* d_ws, size_t ws_size,
                              hipStream_t stream) {
  const float* x  = (const float*)d_in[0];
  const float* Wq = (const float*)d_in[1];
  const float* Wk = (const float*)d_in[2];
  const float* Wv = (const float*)d_in[3];
  float* out = (float*)d_out;
  char* ws = (char*)d_ws;

  bf16_t* wt = (bf16_t*)(ws + WT_OFF);
  bf16_t* qb = (bf16_t*)(ws + Q_OFF);
  bf16_t* kb = (bf16_t*)(ws + K_OFF);
  bf16_t* vT = (bf16_t*)(ws + VT_OFF);

  hipLaunchKernelGGL(wt_kernel, dim3(48), dim3(256), 0, stream, Wq, Wk, Wv, wt);
  hipLaunchKernelGGL(proj_kernel, dim3(768), dim3(256), 0, stream, x, wt, qb, kb, vT);
  hipLaunchKernelGGL(attn_kernel, dim3(512), dim3(512), 0, stream, qb, kb, vT, out);
}